// Round 23
// baseline (37.984 us; speedup 1.0000x reference)
//
#include <hip/hip_runtime.h>
#include <hip/hip_bf16.h>
#include <climits>

typedef __bf16 bf16;
typedef __bf16 bf16x4 __attribute__((ext_vector_type(4)));
typedef __bf16 bf16x8 __attribute__((ext_vector_type(8)));
typedef float f32x4 __attribute__((ext_vector_type(4)));

#define NB 8
#define L_ 4096
#define C_ 512
#define KW 5
#define NS 8
#define BM 64

// ---------------------------------------------------------------------------
// prep (merged): blocks 0..127 pack w_pw -> bf16 MFMA B-frag order;
//                blocks 128..639 compute bias2[n] = b_pw[n] + w_pw[n,:].b_dw
// ---------------------------------------------------------------------------
__global__ __launch_bounds__(256) void prep_kernel(
    const float* __restrict__ w_pw, const float* __restrict__ b_dw,
    const float* __restrict__ b_pw, bf16* __restrict__ pk,
    float* __restrict__ bias2) {
  const int t = threadIdx.x;
  if (blockIdx.x < 128) {
    const int gid = blockIdx.x * 256 + t;  // 0..32767
    const int lane = gid & 63;
    const int nf = (gid >> 6) & 3;
    const int wnn = (gid >> 8) & 7;
    const int kk = gid >> 11;
    const int n = wnn * 64 + nf * 16 + (lane & 15);
    const int c = kk * 32 + (lane >> 4) * 8;
    const float* s = w_pw + n * C_ + c;
    float4 a = *(const float4*)s;
    float4 b4 = *(const float4*)(s + 4);
    bf16x8 h;
    h[0] = (bf16)a.x; h[1] = (bf16)a.y; h[2] = (bf16)a.z; h[3] = (bf16)a.w;
    h[4] = (bf16)b4.x; h[5] = (bf16)b4.y; h[6] = (bf16)b4.z; h[7] = (bf16)b4.w;
    *(bf16x8*)(pk + (size_t)gid * 8) = h;
  } else {
    const int n = blockIdx.x - 128;  // 0..511
    float2 v = *(const float2*)(w_pw + n * C_ + 2 * t);
    float2 bb = *(const float2*)(b_dw + 2 * t);
    float s = v.x * bb.x + v.y * bb.y;
#pragma unroll
    for (int off = 32; off; off >>= 1) s += __shfl_down(s, off, 64);
    __shared__ float part[4];
    if ((t & 63) == 0) part[t >> 6] = s;
    __syncthreads();
    if (t == 0) bias2[n] = b_pw[n] + part[0] + part[1] + part[2] + part[3];
  }
}

// ---------------------------------------------------------------------------
// fused (R22 structure, 37.9 µs) + XCD-aware swizzle (deconfounded from
// R19's nontemporal stores):
//  tile = (bid&7)*64 + (bid>>3): with round-robin dispatch, XCD k processes
//  batch row k -> x reads + 25% halo re-reads localize in its 4MB L2.
//  Phase A: register rolling-window segment-causal conv, 64 rows x 512 ch
//           -> LDS A-tile (bf16, chunk-XOR swizzle), 3-deep prefetch.
//           bb(0) + bias2 issued BEFORE the barrier.
//  ONE __syncthreads().
//  Phase B: barrier-free GEMM, 1Mx8N, acc[4][4]; B-frags ping-pong
//           prefetched one K-step ahead.
// Grid: 512 blocks x 512 thr; As=64KB -> 2 blocks/CU, 16 waves/CU.
// ---------------------------------------------------------------------------
__global__ __launch_bounds__(512, 4) void fused_kernel(
    const float* __restrict__ x, const int* __restrict__ segb,
    const float* __restrict__ w_dw, const bf16* __restrict__ pk,
    const float* __restrict__ bias2, float* __restrict__ out) {
  __shared__ __align__(16) bf16 As[BM * C_];  // 64 KB

  const int t = threadIdx.x;
  const int lane = t & 63;
  const int bid = blockIdx.x;
  const int tile = (bid & 7) * 64 + (bid >> 3);  // XCD k <- batch row k
  const int b = tile >> 6;
  const int l0 = (tile & 63) << 6;

  // ---- Phase-B constants + early loads (independent of As)
  const int wn = t >> 6;     // 0..7
  const int cg = lane >> 4;  // k-chunk group
  const int rx = lane & 7;
  const bf16* pw = pk + (size_t)wn * 2048 + lane * 8;

  bf16x8 bbA[4], bbB[4];
#pragma unroll
  for (int nf = 0; nf < 4; ++nf)
    bbA[nf] = *(const bf16x8*)(pw + nf * 512);  // bb(0): in flight over conv
  const int col0 = wn * 64 + (lane & 15);
  float bia[4];
#pragma unroll
  for (int nf = 0; nf < 4; ++nf) bia[nf] = bias2[col0 + nf * 16];

  // ================= Phase A: conv -> As =================
  const int q = t & 127;         // channel quad (4 ch)
  const int r0 = (t >> 7) << 4;  // row strip 0/16/32/48

  float4 raw[5];
#pragma unroll
  for (int i = 0; i < 5; ++i)
    raw[i] = *(const float4*)(w_dw + q * 20 + i * 4);
  f32x4 wt[5];
#pragma unroll
  for (int m = 0; m < 5; ++m)
#pragma unroll
    for (int i = 0; i < 4; ++i) {
      const int f = i * 5 + m;
      wt[m][i] = ((const float*)&raw[f >> 2])[f & 3];
    }

  const int* sb = segb + b * NS * 2;
  int stv[NS];
#pragma unroll
  for (int s = 0; s < NS; ++s) stv[s] = sb[2 * s];
  auto nxt = [&](int l) {
    int nn = INT_MAX;
#pragma unroll
    for (int s = 0; s < NS; ++s)
      nn = (stv[s] > l && stv[s] < nn) ? stv[s] : nn;
    return nn;
  };
  int ns = nxt(l0 + r0 - 4);

  const float* gxb = x + (size_t)(b * L_ + l0 + r0) * C_ + q * 4;

  const f32x4 z4 = (f32x4){0.f, 0.f, 0.f, 0.f};
  f32x4 w0 = z4, w1 = z4, w2 = z4, w3 = z4;

  // 3-deep row-group prefetch buffers
  f32x4 p0[4], p1[4], p2[4];
  auto ldg = [&](int g, f32x4 (&p)[4]) {
#pragma unroll
    for (int j = 0; j < 4; ++j)
      p[j] = *(const f32x4*)(gxb + (ptrdiff_t)(g * 4 + j) * C_);
  };
  ldg(0, p0);
  ldg(1, p1);
  ldg(2, p2);

  // warmup rows l0+r0-4 .. l0+r0-1 (zero left edge / segment resets)
#pragma unroll
  for (int i = 0; i < 4; ++i) {
    const int l = l0 + r0 - 4 + i;
    f32x4 nv = z4;
    if (l >= 0) nv = *(const f32x4*)(gxb + (ptrdiff_t)(i - 4) * C_);
    if (l == ns) { w0 = z4; w1 = z4; w2 = z4; w3 = z4; ns = nxt(l); }
    w0 = w1; w1 = w2; w2 = w3; w3 = nv;
  }

  auto dorow = [&](int l, f32x4& A, f32x4& B4, f32x4& Cc, f32x4& D,
                   const f32x4& E, int rloc) {
    if (l == ns) { A = z4; B4 = z4; Cc = z4; D = z4; ns = nxt(l); }
    f32x4 r;
#pragma unroll
    for (int i = 0; i < 4; ++i) {
      float a = A[i] * wt[0][i];
      a = fmaf(B4[i], wt[1][i], a);
      a = fmaf(Cc[i], wt[2][i], a);
      a = fmaf(D[i], wt[3][i], a);
      a = fmaf(E[i], wt[4][i], a);
      r[i] = a;
    }
    bf16x4 h;
#pragma unroll
    for (int i = 0; i < 4; ++i) h[i] = (bf16)r[i];
    const int u = q ^ ((rloc & 7) << 1);  // quad-unit XOR swizzle
    *(bf16x4*)&As[rloc * 512 + u * 4] = h;
  };

  auto compute = [&](int g, f32x4 (&p)[4]) {
    const int lb = l0 + r0 + g * 4;
    dorow(lb + 0, w0, w1, w2, w3, p[0], r0 + g * 4 + 0);
    dorow(lb + 1, w1, w2, w3, p[0], p[1], r0 + g * 4 + 1);
    dorow(lb + 2, w2, w3, p[0], p[1], p[2], r0 + g * 4 + 2);
    dorow(lb + 3, w3, p[0], p[1], p[2], p[3], r0 + g * 4 + 3);
    w0 = p[0]; w1 = p[1]; w2 = p[2]; w3 = p[3];
  };

  compute(0, p0);
  ldg(3, p0);  // reuse p0 for the last group
  compute(1, p1);
  compute(2, p2);
  compute(3, p0);

  __syncthreads();  // the ONLY barrier: As now read-only

  // ================= Phase B: GEMM with B ping-pong prefetch ==============
  int aRow[4];
#pragma unroll
  for (int mf = 0; mf < 4; ++mf) aRow[mf] = (mf * 16 + (lane & 15)) * 512;

  f32x4 acc[4][4];
#pragma unroll
  for (int i = 0; i < 4; ++i)
#pragma unroll
    for (int j = 0; j < 4; ++j) acc[i][j] = z4;

#pragma unroll 1
  for (int kk = 0; kk < 16; kk += 2) {
    // even step: prefetch bb(kk+1), compute with bbA
#pragma unroll
    for (int nf = 0; nf < 4; ++nf)
      bbB[nf] = *(const bf16x8*)(pw + (kk + 1) * 16384 + nf * 512);
    {
      const int ao = ((kk * 4 + cg) ^ rx) << 3;
      bf16x8 af[4];
#pragma unroll
      for (int mf = 0; mf < 4; ++mf)
        af[mf] = *(const bf16x8*)&As[aRow[mf] + ao];
      __builtin_amdgcn_s_setprio(1);
#pragma unroll
      for (int nf = 0; nf < 4; ++nf)
#pragma unroll
        for (int mf = 0; mf < 4; ++mf)
          acc[mf][nf] = __builtin_amdgcn_mfma_f32_16x16x32_bf16(
              af[mf], bbA[nf], acc[mf][nf], 0, 0, 0);
      __builtin_amdgcn_s_setprio(0);
    }
    // odd step: prefetch bb(kk+2), compute with bbB
    if (kk + 2 < 16) {
#pragma unroll
      for (int nf = 0; nf < 4; ++nf)
        bbA[nf] = *(const bf16x8*)(pw + (kk + 2) * 16384 + nf * 512);
    }
    {
      const int ao = (((kk + 1) * 4 + cg) ^ rx) << 3;
      bf16x8 af[4];
#pragma unroll
      for (int mf = 0; mf < 4; ++mf)
        af[mf] = *(const bf16x8*)&As[aRow[mf] + ao];
      __builtin_amdgcn_s_setprio(1);
#pragma unroll
      for (int nf = 0; nf < 4; ++nf)
#pragma unroll
        for (int mf = 0; mf < 4; ++mf)
          acc[mf][nf] = __builtin_amdgcn_mfma_f32_16x16x32_bf16(
              af[mf], bbB[nf], acc[mf][nf], 0, 0, 0);
      __builtin_amdgcn_s_setprio(0);
    }
  }

  // ---- epilogue: fp32 + bias2 (b_pw + W.b_dw folded, fp32-exact)
  const int rb0 = l0 + (cg << 2);
#pragma unroll
  for (int mf = 0; mf < 4; ++mf) {
#pragma unroll
    for (int i = 0; i < 4; ++i) {
      const int row = rb0 + mf * 16 + i;
      float* o = out + (size_t)(b * L_ + row) * C_ + col0;
#pragma unroll
      for (int nf = 0; nf < 4; ++nf) o[nf * 16] = acc[mf][nf][i] + bia[nf];
    }
  }
}

extern "C" void kernel_launch(void* const* d_in, const int* in_sizes, int n_in,
                              void* d_out, int out_size, void* d_ws,
                              size_t ws_size, hipStream_t stream) {
  const float* x = (const float*)d_in[0];
  const int* segb = (const int*)d_in[1];      // [B][S][2] int32
  const float* w_dw = (const float*)d_in[2];  // [C][K]
  const float* b_dw = (const float*)d_in[3];  // [C]
  const float* w_pw = (const float*)d_in[4];  // [C_out][C_in]
  const float* b_pw = (const float*)d_in[5];  // [C]
  float* out = (float*)d_out;

  float* bias2 = (float*)d_ws;             // 4 KB
  bf16* pk = (bf16*)((char*)d_ws + 4096);  // 512 KB packed B

  prep_kernel<<<640, 256, 0, stream>>>(w_pw, b_dw, b_pw, pk, bias2);
  fused_kernel<<<NB * L_ / BM, 512, 0, stream>>>(x, segb, w_dw, pk, bias2,
                                                 out);
}

// Round 24
// 37.604 us; speedup vs baseline: 1.0101x; 1.0101x over previous
//
#include <hip/hip_runtime.h>
#include <hip/hip_bf16.h>
#include <climits>

typedef __bf16 bf16;
typedef __bf16 bf16x4 __attribute__((ext_vector_type(4)));
typedef __bf16 bf16x8 __attribute__((ext_vector_type(8)));
typedef float f32x4 __attribute__((ext_vector_type(4)));

#define NB 8
#define L_ 4096
#define C_ 512
#define KW 5
#define NS 8
#define BM 64

// ---------------------------------------------------------------------------
// prep (merged): blocks 0..127 pack w_pw -> bf16 MFMA B-frag order;
//                blocks 128..639 compute bias2[n] = b_pw[n] + w_pw[n,:].b_dw
// ---------------------------------------------------------------------------
__global__ __launch_bounds__(256) void prep_kernel(
    const float* __restrict__ w_pw, const float* __restrict__ b_dw,
    const float* __restrict__ b_pw, bf16* __restrict__ pk,
    float* __restrict__ bias2) {
  const int t = threadIdx.x;
  if (blockIdx.x < 128) {
    const int gid = blockIdx.x * 256 + t;  // 0..32767
    const int lane = gid & 63;
    const int nf = (gid >> 6) & 3;
    const int wnn = (gid >> 8) & 7;
    const int kk = gid >> 11;
    const int n = wnn * 64 + nf * 16 + (lane & 15);
    const int c = kk * 32 + (lane >> 4) * 8;
    const float* s = w_pw + n * C_ + c;
    float4 a = *(const float4*)s;
    float4 b4 = *(const float4*)(s + 4);
    bf16x8 h;
    h[0] = (bf16)a.x; h[1] = (bf16)a.y; h[2] = (bf16)a.z; h[3] = (bf16)a.w;
    h[4] = (bf16)b4.x; h[5] = (bf16)b4.y; h[6] = (bf16)b4.z; h[7] = (bf16)b4.w;
    *(bf16x8*)(pk + (size_t)gid * 8) = h;
  } else {
    const int n = blockIdx.x - 128;  // 0..511
    float2 v = *(const float2*)(w_pw + n * C_ + 2 * t);
    float2 bb = *(const float2*)(b_dw + 2 * t);
    float s = v.x * bb.x + v.y * bb.y;
#pragma unroll
    for (int off = 32; off; off >>= 1) s += __shfl_down(s, off, 64);
    __shared__ float part[4];
    if ((t & 63) == 0) part[t >> 6] = s;
    __syncthreads();
    if (t == 0) bias2[n] = b_pw[n] + part[0] + part[1] + part[2] + part[3];
  }
}

// ---------------------------------------------------------------------------
// fused (final form, 37.9 µs):
//  Phase A: register rolling-window segment-causal conv, 64 rows x 512 ch
//           -> LDS A-tile (bf16, chunk-XOR swizzle), 3-deep row-group
//           prefetch. bb(0) + bias2 issued BEFORE the barrier (independent
//           of As; ride the conv drain).
//  ONE __syncthreads().
//  Phase B: barrier-free GEMM, 1Mx8N: 8 waves x (64 rows x 64 cols),
//           acc[4][4]; B-frags ping-pong prefetched one K-step ahead
//           (full-iteration slack for the ~200cy L2 latency).
// Grid: 512 blocks x 512 thr; As=64KB -> 2 blocks/CU, 16 waves/CU.
// ---------------------------------------------------------------------------
__global__ __launch_bounds__(512, 4) void fused_kernel(
    const float* __restrict__ x, const int* __restrict__ segb,
    const float* __restrict__ w_dw, const bf16* __restrict__ pk,
    const float* __restrict__ bias2, float* __restrict__ out) {
  __shared__ __align__(16) bf16 As[BM * C_];  // 64 KB

  const int t = threadIdx.x;
  const int lane = t & 63;
  const int b = blockIdx.x >> 6;          // 64 m-tiles per batch row
  const int l0 = (blockIdx.x & 63) << 6;  // tile * 64

  // ---- Phase-B constants + early loads (independent of As)
  const int wn = t >> 6;     // 0..7
  const int cg = lane >> 4;  // k-chunk group
  const int rx = lane & 7;
  const bf16* pw = pk + (size_t)wn * 2048 + lane * 8;

  bf16x8 bbA[4], bbB[4];
#pragma unroll
  for (int nf = 0; nf < 4; ++nf)
    bbA[nf] = *(const bf16x8*)(pw + nf * 512);  // bb(0): in flight over conv
  const int col0 = wn * 64 + (lane & 15);
  float bia[4];
#pragma unroll
  for (int nf = 0; nf < 4; ++nf) bia[nf] = bias2[col0 + nf * 16];

  // ================= Phase A: conv -> As =================
  const int q = t & 127;         // channel quad (4 ch)
  const int r0 = (t >> 7) << 4;  // row strip 0/16/32/48

  float4 raw[5];
#pragma unroll
  for (int i = 0; i < 5; ++i)
    raw[i] = *(const float4*)(w_dw + q * 20 + i * 4);
  f32x4 wt[5];
#pragma unroll
  for (int m = 0; m < 5; ++m)
#pragma unroll
    for (int i = 0; i < 4; ++i) {
      const int f = i * 5 + m;
      wt[m][i] = ((const float*)&raw[f >> 2])[f & 3];
    }

  const int* sb = segb + b * NS * 2;
  int stv[NS];
#pragma unroll
  for (int s = 0; s < NS; ++s) stv[s] = sb[2 * s];
  auto nxt = [&](int l) {
    int nn = INT_MAX;
#pragma unroll
    for (int s = 0; s < NS; ++s)
      nn = (stv[s] > l && stv[s] < nn) ? stv[s] : nn;
    return nn;
  };
  int ns = nxt(l0 + r0 - 4);

  const float* gxb = x + (size_t)(b * L_ + l0 + r0) * C_ + q * 4;

  const f32x4 z4 = (f32x4){0.f, 0.f, 0.f, 0.f};
  f32x4 w0 = z4, w1 = z4, w2 = z4, w3 = z4;

  // 3-deep row-group prefetch buffers
  f32x4 p0[4], p1[4], p2[4];
  auto ldg = [&](int g, f32x4 (&p)[4]) {
#pragma unroll
    for (int j = 0; j < 4; ++j)
      p[j] = *(const f32x4*)(gxb + (ptrdiff_t)(g * 4 + j) * C_);
  };
  ldg(0, p0);
  ldg(1, p1);
  ldg(2, p2);

  // warmup rows l0+r0-4 .. l0+r0-1 (zero left edge / segment resets)
#pragma unroll
  for (int i = 0; i < 4; ++i) {
    const int l = l0 + r0 - 4 + i;
    f32x4 nv = z4;
    if (l >= 0) nv = *(const f32x4*)(gxb + (ptrdiff_t)(i - 4) * C_);
    if (l == ns) { w0 = z4; w1 = z4; w2 = z4; w3 = z4; ns = nxt(l); }
    w0 = w1; w1 = w2; w2 = w3; w3 = nv;
  }

  auto dorow = [&](int l, f32x4& A, f32x4& B4, f32x4& Cc, f32x4& D,
                   const f32x4& E, int rloc) {
    if (l == ns) { A = z4; B4 = z4; Cc = z4; D = z4; ns = nxt(l); }
    f32x4 r;
#pragma unroll
    for (int i = 0; i < 4; ++i) {
      float a = A[i] * wt[0][i];
      a = fmaf(B4[i], wt[1][i], a);
      a = fmaf(Cc[i], wt[2][i], a);
      a = fmaf(D[i], wt[3][i], a);
      a = fmaf(E[i], wt[4][i], a);
      r[i] = a;
    }
    bf16x4 h;
#pragma unroll
    for (int i = 0; i < 4; ++i) h[i] = (bf16)r[i];
    const int u = q ^ ((rloc & 7) << 1);  // quad-unit XOR swizzle
    *(bf16x4*)&As[rloc * 512 + u * 4] = h;
  };

  auto compute = [&](int g, f32x4 (&p)[4]) {
    const int lb = l0 + r0 + g * 4;
    dorow(lb + 0, w0, w1, w2, w3, p[0], r0 + g * 4 + 0);
    dorow(lb + 1, w1, w2, w3, p[0], p[1], r0 + g * 4 + 1);
    dorow(lb + 2, w2, w3, p[0], p[1], p[2], r0 + g * 4 + 2);
    dorow(lb + 3, w3, p[0], p[1], p[2], p[3], r0 + g * 4 + 3);
    w0 = p[0]; w1 = p[1]; w2 = p[2]; w3 = p[3];
  };

  compute(0, p0);
  ldg(3, p0);  // reuse p0 for the last group
  compute(1, p1);
  compute(2, p2);
  compute(3, p0);

  __syncthreads();  // the ONLY barrier: As now read-only

  // ================= Phase B: GEMM with B ping-pong prefetch ==============
  int aRow[4];
#pragma unroll
  for (int mf = 0; mf < 4; ++mf) aRow[mf] = (mf * 16 + (lane & 15)) * 512;

  f32x4 acc[4][4];
#pragma unroll
  for (int i = 0; i < 4; ++i)
#pragma unroll
    for (int j = 0; j < 4; ++j) acc[i][j] = z4;

#pragma unroll 1
  for (int kk = 0; kk < 16; kk += 2) {
    // even step: prefetch bb(kk+1), compute with bbA
#pragma unroll
    for (int nf = 0; nf < 4; ++nf)
      bbB[nf] = *(const bf16x8*)(pw + (kk + 1) * 16384 + nf * 512);
    {
      const int ao = ((kk * 4 + cg) ^ rx) << 3;
      bf16x8 af[4];
#pragma unroll
      for (int mf = 0; mf < 4; ++mf)
        af[mf] = *(const bf16x8*)&As[aRow[mf] + ao];
      __builtin_amdgcn_s_setprio(1);
#pragma unroll
      for (int nf = 0; nf < 4; ++nf)
#pragma unroll
        for (int mf = 0; mf < 4; ++mf)
          acc[mf][nf] = __builtin_amdgcn_mfma_f32_16x16x32_bf16(
              af[mf], bbA[nf], acc[mf][nf], 0, 0, 0);
      __builtin_amdgcn_s_setprio(0);
    }
    // odd step: prefetch bb(kk+2), compute with bbB
    if (kk + 2 < 16) {
#pragma unroll
      for (int nf = 0; nf < 4; ++nf)
        bbA[nf] = *(const bf16x8*)(pw + (kk + 2) * 16384 + nf * 512);
    }
    {
      const int ao = (((kk + 1) * 4 + cg) ^ rx) << 3;
      bf16x8 af[4];
#pragma unroll
      for (int mf = 0; mf < 4; ++mf)
        af[mf] = *(const bf16x8*)&As[aRow[mf] + ao];
      __builtin_amdgcn_s_setprio(1);
#pragma unroll
      for (int nf = 0; nf < 4; ++nf)
#pragma unroll
        for (int mf = 0; mf < 4; ++mf)
          acc[mf][nf] = __builtin_amdgcn_mfma_f32_16x16x32_bf16(
              af[mf], bbB[nf], acc[mf][nf], 0, 0, 0);
      __builtin_amdgcn_s_setprio(0);
    }
  }

  // ---- epilogue: fp32 + bias2 (b_pw + W.b_dw folded, fp32-exact)
  const int rb0 = l0 + (cg << 2);
#pragma unroll
  for (int mf = 0; mf < 4; ++mf) {
#pragma unroll
    for (int i = 0; i < 4; ++i) {
      const int row = rb0 + mf * 16 + i;
      float* o = out + (size_t)(b * L_ + row) * C_ + col0;
#pragma unroll
      for (int nf = 0; nf < 4; ++nf) o[nf * 16] = acc[mf][nf][i] + bia[nf];
    }
  }
}

extern "C" void kernel_launch(void* const* d_in, const int* in_sizes, int n_in,
                              void* d_out, int out_size, void* d_ws,
                              size_t ws_size, hipStream_t stream) {
  const float* x = (const float*)d_in[0];
  const int* segb = (const int*)d_in[1];      // [B][S][2] int32
  const float* w_dw = (const float*)d_in[2];  // [C][K]
  const float* b_dw = (const float*)d_in[3];  // [C]
  const float* w_pw = (const float*)d_in[4];  // [C_out][C_in]
  const float* b_pw = (const float*)d_in[5];  // [C]
  float* out = (float*)d_out;

  float* bias2 = (float*)d_ws;             // 4 KB
  bf16* pk = (bf16*)((char*)d_ws + 4096);  // 512 KB packed B

  prep_kernel<<<640, 256, 0, stream>>>(w_pw, b_dw, b_pw, pk, bias2);
  fused_kernel<<<NB * L_ / BM, 512, 0, stream>>>(x, segb, w_dw, pk, bias2,
                                                 out);
}